// Round 10
// baseline (927.485 us; speedup 1.0000x reference)
//
#include <hip/hip_runtime.h>
#include <cstdint>

#define N_NODES 50000
#define N_EDGES 800000
#define DIM 128
#define KSEL 5000
#define MCONST (2 * N_EDGES + 2)   // 1600002
#define PCH 256     // pool chunk (members per block)
#define MCH 16      // coarse-SpMM chunk (members per block)
#define CANDCAP 8192
#define TM 4        // rows per thread in tiled GEMM (block covers 32 rows)

typedef unsigned long long u64;
typedef uint32_t u32;

// ---------- tiled GEMM core: Y[r][c] = sum_k X[r][k]*W[k][c], W is 128x128 ----
#define FMA4(a, s, w) { a.x = fmaf(s, w.x, a.x); a.y = fmaf(s, w.y, a.y); \
                        a.z = fmaf(s, w.z, a.z); a.w = fmaf(s, w.w, a.w); }

__device__ __forceinline__ void gemm_tile_body(const float4* __restrict__ W4,
                                               float xs[32][DIM], float4 acc[TM],
                                               int tx, int ty) {
#pragma unroll 8
  for (int k4 = 0; k4 < 32; k4++) {
    float4 xv[TM];
#pragma unroll
    for (int m = 0; m < TM; m++) xv[m] = *(const float4*)&xs[ty + 8 * m][k4 * 4];
#pragma unroll
    for (int j = 0; j < 4; j++) {
      float4 w = W4[(k4 * 4 + j) * 32 + tx];
#pragma unroll
      for (int m = 0; m < TM; m++) {
        float s = (j == 0) ? xv[m].x : (j == 1) ? xv[m].y : (j == 2) ? xv[m].z : xv[m].w;
        FMA4(acc[m], s, w);
      }
    }
  }
}

__global__ void gemm_tiled(const float* __restrict__ X, const float* __restrict__ W,
                           float* __restrict__ Y, int nrows) {
  __shared__ float xs[32][DIM];
  int tx = threadIdx.x & 31, ty = threadIdx.x >> 5;
  int rbase = blockIdx.x * 32;
  int nval = min(32, nrows - rbase);
  const float4* X4 = (const float4*)(X + (size_t)rbase * DIM);
  float4* xs4 = (float4*)&xs[0][0];
  for (int i = threadIdx.x; i < 32 * 32; i += 256)
    if ((i >> 5) < nval) xs4[i] = X4[i];
  __syncthreads();
  float4 acc[TM];
#pragma unroll
  for (int m = 0; m < TM; m++) acc[m] = make_float4(0.f, 0.f, 0.f, 0.f);
  gemm_tile_body((const float4*)W, xs, acc, tx, ty);
#pragma unroll
  for (int m = 0; m < TM; m++) {
    int r = rbase + ty + 8 * m;
    if (r < nrows) ((float4*)(Y + (size_t)r * DIM))[tx] = acc[m];
  }
}

// variant: rows pre-divided by counts (mean pool) during staging
__global__ void gemm_tiled_div(const float* __restrict__ S, const int* __restrict__ counts,
                               const float* __restrict__ W, float* __restrict__ Y, int nrows) {
  __shared__ float xs[32][DIM];
  int tx = threadIdx.x & 31, ty = threadIdx.x >> 5;
  int rbase = blockIdx.x * 32;
  int nval = min(32, nrows - rbase);
  const float4* X4 = (const float4*)(S + (size_t)rbase * DIM);
  float4* xs4 = (float4*)&xs[0][0];
  for (int i = threadIdx.x; i < 32 * 32; i += 256) {
    int rr = i >> 5;
    if (rr < nval) {
      float inv = 1.0f / (float)max(counts[rbase + rr], 1);
      float4 v = X4[i];
      v.x *= inv; v.y *= inv; v.z *= inv; v.w *= inv;
      xs4[i] = v;
    }
  }
  __syncthreads();
  float4 acc[TM];
#pragma unroll
  for (int m = 0; m < TM; m++) acc[m] = make_float4(0.f, 0.f, 0.f, 0.f);
  gemm_tile_body((const float4*)W, xs, acc, tx, ty);
#pragma unroll
  for (int m = 0; m < TM; m++) {
    int r = rbase + ty + 8 * m;
    if (r < nrows) ((float4*)(Y + (size_t)r * DIM))[tx] = acc[m];
  }
}

// variant: epilogue adds b_skip and xp2[cluster[r]] (the broadcast+skip fusion)
__global__ void final_tiled(const float* __restrict__ x1, const float* __restrict__ Wsk,
                            const float* __restrict__ bsk, const float* __restrict__ xp2,
                            const int* __restrict__ cluster, float* __restrict__ out) {
  __shared__ float xs[32][DIM];
  int tx = threadIdx.x & 31, ty = threadIdx.x >> 5;
  int rbase = blockIdx.x * 32;
  int nval = min(32, N_NODES - rbase);
  const float4* X4 = (const float4*)(x1 + (size_t)rbase * DIM);
  float4* xs4 = (float4*)&xs[0][0];
  for (int i = threadIdx.x; i < 32 * 32; i += 256)
    if ((i >> 5) < nval) xs4[i] = X4[i];
  __syncthreads();
  float4 acc[TM];
#pragma unroll
  for (int m = 0; m < TM; m++) acc[m] = make_float4(0.f, 0.f, 0.f, 0.f);
  gemm_tile_body((const float4*)Wsk, xs, acc, tx, ty);
  float4 bv = ((const float4*)bsk)[tx];
#pragma unroll
  for (int m = 0; m < TM; m++) {
    int r = rbase + ty + 8 * m;
    if (r < N_NODES) {
      int cl = cluster[r];
      cl = (cl < 0) ? 0 : (cl >= KSEL ? KSEL - 1 : cl);   // defensive clamp
      float4 pv = ((const float4*)(xp2 + (size_t)cl * DIM))[tx];
      float4 o;
      o.x = acc[m].x + bv.x + pv.x;
      o.y = acc[m].y + bv.y + pv.y;
      o.z = acc[m].z + bv.z + pv.z;
      o.w = acc[m].w + bv.w + pv.w;
      ((float4*)(out + (size_t)r * DIM))[tx] = o;
    }
  }
  if (blockIdx.x == 0 && threadIdx.x == 0) out[(size_t)N_NODES * DIM] = 0.0f;  // tuple scalar
}

// ---------------- degree counts ----------------
__global__ void deg_kernel(const int* __restrict__ row, const int* __restrict__ col,
                           int* deg1, int* deg2) {
  int e = blockIdx.x * blockDim.x + threadIdx.x;
  if (e < N_EDGES) {
    atomicAdd(&deg1[col[e]], 1);   // in-degree at col (GCN norm)
    atomicAdd(&deg2[row[e]], 1);   // bincount(row) (topk-pool degree)
  }
}

__global__ void rsqrt_kernel(const int* __restrict__ deg, float* __restrict__ dinv, int n) {
  int i = blockIdx.x * blockDim.x + threadIdx.x;
  if (i < n) dinv[i] = rsqrtf((float)deg[i] + 1.0f);
}

// ---------------- hierarchical exclusive scan (N_NODES) ----------------
__global__ void scan_local(const int* __restrict__ in, int* __restrict__ out,
                           int* __restrict__ bsum, int n) {
  __shared__ int s[256];
  int i = blockIdx.x * 256 + threadIdx.x;
  int v = (i < n) ? in[i] : 0;
  s[threadIdx.x] = v;
  __syncthreads();
  for (int off = 1; off < 256; off <<= 1) {
    int t = (threadIdx.x >= off) ? s[threadIdx.x - off] : 0;
    __syncthreads();
    s[threadIdx.x] += t;
    __syncthreads();
  }
  if (i < n) out[i] = s[threadIdx.x] - v;   // exclusive
  if (threadIdx.x == 255) bsum[blockIdx.x] = s[255];
}

__global__ void scan_bsum(int* bsum, int nb) {
  __shared__ int s[256];
  int v = (threadIdx.x < nb) ? bsum[threadIdx.x] : 0;
  s[threadIdx.x] = v;
  __syncthreads();
  for (int off = 1; off < 256; off <<= 1) {
    int t = (threadIdx.x >= off) ? s[threadIdx.x - off] : 0;
    __syncthreads();
    s[threadIdx.x] += t;
    __syncthreads();
  }
  if (threadIdx.x < nb) bsum[threadIdx.x] = s[threadIdx.x] - v;
}

__global__ void scan_add(int* out, const int* __restrict__ bsum, int n) {
  int i = blockIdx.x * 256 + threadIdx.x;
  if (i < n) out[i] += bsum[blockIdx.x];
}

// ---------------- single-block exclusive scan (n ~ 5000), writes out[n]=total -
__global__ void scan_small(const int* __restrict__ in, int* __restrict__ out, int n) {
  __shared__ int s[256];
  __shared__ int carry;
  if (threadIdx.x == 0) carry = 0;
  __syncthreads();
  for (int base = 0; base < n; base += 256) {
    int i = base + threadIdx.x;
    int v = (i < n) ? in[i] : 0;
    s[threadIdx.x] = v;
    __syncthreads();
    for (int off = 1; off < 256; off <<= 1) {
      int t = (threadIdx.x >= off) ? s[threadIdx.x - off] : 0;
      __syncthreads();
      s[threadIdx.x] += t;
      __syncthreads();
    }
    int c = carry;
    if (i < n) out[i] = c + s[threadIdx.x] - v;
    __syncthreads();
    if (threadIdx.x == 255) carry = c + s[255];
    __syncthreads();
  }
  if (threadIdx.x == 0) out[n] = carry;
}

// ---------------- CSR fills ----------------
__global__ void fill_ecsr(const int* __restrict__ row, const int* __restrict__ col,
                          const int* __restrict__ start, int* cursor, int* payload) {
  int e = blockIdx.x * blockDim.x + threadIdx.x;
  if (e < N_EDGES) {
    int c = col[e];
    int p = start[c] + atomicAdd(&cursor[c], 1);
    if (p >= 0 && p < N_EDGES) payload[p] = row[e];    // defensive bound
  }
}

__global__ void fill_members(const int* __restrict__ cluster, const int* __restrict__ startn,
                             int* cursorn, int* members) {
  int i = blockIdx.x * blockDim.x + threadIdx.x;
  if (i < N_NODES) {
    int c = cluster[i];
    int p = startn[c] + atomicAdd(&cursorn[c], 1);
    if (p >= 0 && p < N_NODES) members[p] = i;         // defensive bound
  }
}

// ---------------- GCN1 gather + combine + relu + score + key (fused) ---------
__global__ void gcn1_gather(const int* __restrict__ srcs, const int* __restrict__ start,
                            const int* __restrict__ deg1, const float* __restrict__ dinv,
                            const float* __restrict__ h, const float* __restrict__ b1,
                            const float* __restrict__ wscore,
                            float* __restrict__ B, float* __restrict__ gate,
                            u64* __restrict__ key) {
  int i = blockIdx.x, t = threadIdx.x;
  int s0 = start[i], n = deg1[i];
  float di = dinv[i];
  float acc = 0.f;
  for (int k = 0; k < n; k++) {
    int r = srcs[s0 + k];
    acc = fmaf(dinv[r], h[r * DIM + t], acc);
  }
  float v = acc * di + di * di * h[i * DIM + t] + b1[t];
  v = v > 0.f ? v : 0.f;
  B[i * DIM + t] = v;
  __shared__ float red[DIM];
  red[t] = v * wscore[t];
  __syncthreads();
  for (int s = DIM / 2; s > 0; s >>= 1) {
    if (t < s) red[t] += red[t + s];
    __syncthreads();
  }
  if (t == 0) {
    float r = red[0];
    gate[i] = tanhf(r);
    u32 b = __float_as_uint(r);
    if ((b << 1) == 0u) b = 0u;                          // -0 -> +0
    u32 ord = (b & 0x80000000u) ? ~b : (b | 0x80000000u);
    key[i] = (((u64)(~ord)) << 32) | (u32)i;             // asc = desc value, tie asc idx
  }
}

// ============== top-K selection: radix-select threshold, then rank kept =======
__global__ void hist1_kernel(const u64* __restrict__ key, int* __restrict__ hist) {
  int i = blockIdx.x * blockDim.x + threadIdx.x;
  if (i < N_NODES) atomicAdd(&hist[(int)(key[i] >> 52)], 1);
}

__global__ void hist2_kernel(const u64* __restrict__ key, const int* __restrict__ selb,
                             int* __restrict__ hist) {
  int i = blockIdx.x * blockDim.x + threadIdx.x;
  if (i < N_NODES) {
    u64 k = key[i];
    if ((int)(k >> 52) == selb[0]) atomicAdd(&hist[(int)((k >> 40) & 0xFFF)], 1);
  }
}

__global__ void pick_kernel(const int* __restrict__ hist, int K_imm, int* __restrict__ selb,
                            int rem_in_slot, int bin_out_slot, int rem_out_slot) {
  __shared__ int s[256];
  int t = threadIdx.x;
  int base = t * 16;
  int loc[16];
  int sum = 0;
#pragma unroll
  for (int k = 0; k < 16; k++) { loc[k] = hist[base + k]; sum += loc[k]; }
  s[t] = sum;
  __syncthreads();
  for (int off = 1; off < 256; off <<= 1) {
    int v = (t >= off) ? s[t - off] : 0;
    __syncthreads();
    s[t] += v;
    __syncthreads();
  }
  int target = (K_imm >= 0) ? K_imm : selb[rem_in_slot];
  int prev = (t == 0) ? 0 : s[t - 1];
  if (prev < target && target <= s[t]) {      // exactly one thread
    int cum = prev;
#pragma unroll
    for (int k = 0; k < 16; k++) {
      cum += loc[k];
      if (cum >= target) {
        selb[bin_out_slot] = base + k;
        selb[rem_out_slot] = target - (cum - loc[k]);   // in [1, bincount]
        break;
      }
    }
  }
}

__global__ void collect_kernel(const u64* __restrict__ key, const int* __restrict__ selb,
                               u64* __restrict__ cand, int* __restrict__ ccnt) {
  int i = blockIdx.x * blockDim.x + threadIdx.x;
  if (i < N_NODES) {
    u64 k = key[i];
    if ((int)(k >> 52) == selb[0] && (int)((k >> 40) & 0xFFF) == selb[2]) {
      int p = atomicAdd(ccnt, 1);
      if (p < CANDCAP) cand[p] = k;
    }
  }
}

__global__ void thresh_kernel(const u64* __restrict__ cand, const int* __restrict__ ccnt,
                              const int* __restrict__ selb, u64* __restrict__ T) {
  int c = min(*ccnt, CANDCAP);
  int R = selb[3];
  for (int p = threadIdx.x; p < c; p += 256) {
    u64 kp = cand[p];
    int cnt = 0;
    for (int q = 0; q < c; q++) cnt += (cand[q] < kp) ? 1 : 0;
    if (cnt == R - 1) *T = kp;                           // unique keys: one writer
  }
}

__global__ void compact_kernel(const u64* __restrict__ key, const u64* __restrict__ T,
                               int* __restrict__ krank, u64* __restrict__ kkey,
                               int* __restrict__ kidx, int* __restrict__ kcnt) {
  int i = blockIdx.x * blockDim.x + threadIdx.x;
  if (i < N_NODES) {
    krank[i] = -1;
    u64 k = key[i];
    if (k <= *T) {
      int p = atomicAdd(kcnt, 1);
      if (p < KSEL + 16) {                               // capacity guard
        kkey[p] = k;
        kidx[p] = i;
      }
    }
  }
}

__global__ void krank_kernel(const u64* __restrict__ kkey, const int* __restrict__ kidx,
                             const int* __restrict__ deg2, int* __restrict__ krank,
                             u64* fbkey) {
  int p = blockIdx.x * blockDim.x + threadIdx.x;
  u64 mykey = (p < KSEL) ? kkey[p] : ~0ull;
  __shared__ u64 sk[256];
  int cnt = 0;
  for (int base = 0; base < KSEL; base += 256) {
    int j = base + threadIdx.x;
    sk[threadIdx.x] = (j < KSEL) ? kkey[j] : ~0ull;
    __syncthreads();
    int lim = min(256, KSEL - base);
#pragma unroll 4
    for (int q = 0; q < lim; q++) cnt += (sk[q] < mykey) ? 1 : 0;
    __syncthreads();
  }
  if (p < KSEL) {
    int node = kidx[p];
    if (node >= 0 && node < N_NODES) {                   // defensive bound
      krank[node] = cnt;
      u64 fk = (((u64)(deg2[node] + 1)) << 32) | (u32)(KSEL - 1 - cnt);
      atomicMax(fbkey, fk);
    }
  }
}

// ---------------- best kept neighbor per owner ----------------
__global__ void bestneigh_kernel(const int* __restrict__ row, const int* __restrict__ col,
                                 const int* __restrict__ krank, const int* __restrict__ deg2,
                                 u64* __restrict__ best) {
  int e = blockIdx.x * blockDim.x + threadIdx.x;
  if (e < N_EDGES) {
    int r = row[e], c = col[e];
    if (krank[c] >= 0) {  // (owner=r, neigh=c, order=2e)
      u64 comp = (u64)deg2[c] * (u64)MCONST + (u64)(MCONST - 1 - 2 * e);
      atomicMax(&best[r], comp + 1);
    }
    if (krank[r] >= 0) {  // (owner=c, neigh=r, order=2e+1)
      u64 comp = (u64)deg2[r] * (u64)MCONST + (u64)(MCONST - 2 - 2 * e);
      atomicMax(&best[c], comp + 1);
    }
  }
}

// ---------------- cluster assignment + counts ----------------
__global__ void assign_kernel(const int* __restrict__ krank, const u64* __restrict__ best,
                              const int* __restrict__ row, const int* __restrict__ col,
                              const u64* __restrict__ fbkey,
                              int* __restrict__ cluster, int* __restrict__ counts) {
  int i = blockIdx.x * blockDim.x + threadIdx.x;
  if (i >= N_NODES) return;
  int c;
  int rk = krank[i];
  if (rk >= 0) {
    c = rk;
  } else {
    u64 b = best[i];
    if (b > 0) {
      u64 comp = b - 1;
      int rem = (int)(comp % (u64)MCONST);
      int ord = MCONST - 1 - rem;
      int e = ord >> 1;
      int nb = (ord & 1) ? row[e] : col[e];
      c = krank[nb];
    } else {
      c = KSEL - 1 - (int)((*fbkey) & 0xffffffffu);
    }
  }
  c = (c < 0) ? 0 : (c >= KSEL ? KSEL - 1 : c);          // defensive clamp
  cluster[i] = c;
  atomicAdd(&counts[c], 1);
}

// ---------------- mean pool, merge-path chunked segmented reduction ----------
__global__ void pool_chunk(const int* __restrict__ members, const int* __restrict__ startn,
                           const float* __restrict__ x1, const float* __restrict__ gate,
                           float* __restrict__ sums) {
  int cb = blockIdx.x * PCH;
  if (cb >= N_NODES) return;
  int ce = min(cb + PCH, N_NODES);
  __shared__ int pl[PCH];
  for (int k = threadIdx.x; k < ce - cb; k += DIM) pl[k] = members[cb + k];
  __syncthreads();
  int lo = 0, hi = KSEL - 1;                 // largest c with startn[c] <= cb
  while (lo < hi) { int mid = (lo + hi + 1) >> 1; if (startn[mid] <= cb) lo = mid; else hi = mid - 1; }
  int c = lo;
  int segend = startn[c + 1];
  int t = threadIdx.x;
  float acc = 0.f;
  for (int k = cb; k < ce; k++) {
    int j = pl[k - cb];
    acc = fmaf(gate[j], x1[j * DIM + t], acc);
    int k1 = k + 1;
    if (k1 == segend || k1 == ce) {
      atomicAdd(&sums[c * DIM + t], acc);
      acc = 0.f;
      if (k1 == segend && k1 < ce) {
        while (c < KSEL - 1 && startn[c + 1] <= k1) c++;   // bounded advance
        segend = startn[c + 1];
      }
    }
  }
}

// ---------------- coarse degrees from fine edge-CSR (balanced) ----------------
__global__ void cdeg_kernel(const int* __restrict__ srcs, const int* __restrict__ start,
                            const int* __restrict__ deg1, const int* __restrict__ cluster,
                            int* __restrict__ degc) {
  int v = blockIdx.x * blockDim.x + threadIdx.x;
  if (v >= N_NODES) return;
  int cv = cluster[v];
  int s0 = start[v], n = deg1[v], cnt = 0;
  for (int k = 0; k < n; k++) cnt += (cluster[srcs[s0 + k]] != cv) ? 1 : 0;
  if (cnt) atomicAdd(&degc[cv], cnt);
}

// ---- coarse SpMM: members-ordered chunked segmented reduction over in-edges --
// block = 128 thr handles MCH members (cluster-sorted); register acc flushed
// once per cluster-segment per chunk -> ~8k atomic rows instead of 50k.
__global__ void coarse_chunk(const int* __restrict__ members, const int* __restrict__ startn,
                             const int* __restrict__ cluster, const int* __restrict__ start,
                             const int* __restrict__ deg1, const int* __restrict__ srcs,
                             const float* __restrict__ dinvc, const float* __restrict__ h2,
                             float* __restrict__ agg2) {
  int mb = blockIdx.x * MCH;
  if (mb >= N_NODES) return;
  int me = min(mb + MCH, N_NODES);
  int t = threadIdx.x;
  int lo = 0, hi = KSEL - 1;                 // largest c with startn[c] <= mb
  while (lo < hi) { int mid = (lo + hi + 1) >> 1; if (startn[mid] <= mb) lo = mid; else hi = mid - 1; }
  int c = lo;
  int segend = startn[c + 1];
  float acc = 0.f;
  bool dirty = false;                        // block-uniform
  for (int m = mb; m < me; m++) {
    int v = members[m];
    int s0 = start[v], n = deg1[v];
    for (int k = 0; k < n; k++) {
      int cu = cluster[srcs[s0 + k]];
      if (cu != c) { acc = fmaf(dinvc[cu], h2[cu * DIM + t], acc); dirty = true; }
    }
    int m1 = m + 1;
    if (m1 == segend || m1 == me) {
      if (dirty) atomicAdd(&agg2[c * DIM + t], acc);
      acc = 0.f; dirty = false;
      if (m1 == segend && m1 < me) {
        while (c < KSEL - 1 && startn[c + 1] <= m1) c++;   // bounded advance
        segend = startn[c + 1];
      }
    }
  }
}

// ---------------- combine2: xp2 = agg2*dc + dc*dc*h2 + b2 ----------------
__global__ void combine2(const float* __restrict__ agg2, const float* __restrict__ h2,
                         const float* __restrict__ dinvc, const float* __restrict__ b2,
                         float* __restrict__ xp2) {
  int gid = blockIdx.x * blockDim.x + threadIdx.x;
  int c = gid >> 7, d = gid & 127;
  if (c < KSEL) {
    float dc = dinvc[c];
    xp2[gid] = agg2[gid] * dc + dc * dc * h2[gid] + b2[d];
  }
}

extern "C" void kernel_launch(void* const* d_in, const int* in_sizes, int n_in,
                              void* d_out, int out_size, void* d_ws, size_t ws_size,
                              hipStream_t stream) {
  const float* x      = (const float*)d_in[0];
  const int*   eidx   = (const int*)d_in[1];
  const float* W1     = (const float*)d_in[2];
  const float* b1     = (const float*)d_in[3];
  const float* W2     = (const float*)d_in[4];
  const float* b2     = (const float*)d_in[5];
  const float* wscore = (const float*)d_in[6];
  const float* Wsk    = (const float*)d_in[7];
  const float* bsk    = (const float*)d_in[8];
  float* out = (float*)d_out;

  const int* row = eidx;
  const int* col = eidx + N_EDGES;

  // ---- workspace carve (EVERY offset rounded to 16 B — misaligned u64
  // atomics fault on gfx950) ----
  char* ws = (char*)d_ws;
#define ALIGN16(v) (((v) + 15) & ~(size_t)15)
  size_t off = 0;
#define CARVE(ptr_t, name, bytes) ptr_t name = (ptr_t)(ws + off); off = ALIGN16(off + (bytes))
  size_t h_off = off;
  CARVE(float*, h, (size_t)N_NODES * DIM * 4);        // 25.6 MB (aliased below)
  CARVE(float*, B, (size_t)N_NODES * DIM * 4);        // x1
  CARVE(int*, payload, (size_t)N_EDGES * 4);          // edge CSR (by col)
  CARVE(u64*, key, (size_t)N_NODES * 8);
  CARVE(float*, gate, (size_t)N_NODES * 4);
  CARVE(float*, dinv, (size_t)N_NODES * 4);
  CARVE(int*, start, (size_t)N_NODES * 4);
  CARVE(int*, bsum, 256 * 4);
  // zone A: zero before deg/fill
  size_t zA = off;
  CARVE(int*, deg1, (size_t)N_NODES * 4);
  CARVE(int*, deg2, (size_t)N_NODES * 4);
  CARVE(int*, cursor, (size_t)N_NODES * 4);
  size_t zAsize = off - zA;

  // aliased into h's region (h is dead after gcn1_gather)
  size_t ho = h_off;
#define CARVE2(ptr_t, name, bytes) ptr_t name = (ptr_t)(ws + ho); ho = ALIGN16(ho + (bytes))
  CARVE2(int*, cluster, (size_t)N_NODES * 4);
  CARVE2(int*, members, (size_t)N_NODES * 4);
  CARVE2(int*, startn, (size_t)(KSEL + 1) * 4);
  CARVE2(float*, dinvc, (size_t)KSEL * 4);
  CARVE2(float*, h2, (size_t)KSEL * DIM * 4);
  // zone B: zeroed after gcn1_gather
  size_t zB = ho;
  CARVE2(u64*, best, (size_t)N_NODES * 8);
  CARVE2(int*, counts, (size_t)KSEL * 4);
  CARVE2(int*, degc, (size_t)KSEL * 4);
  CARVE2(int*, cursorn, (size_t)KSEL * 4);
  CARVE2(float*, sums, (size_t)KSEL * DIM * 4);       // pool sums, then xp2
  CARVE2(float*, agg2, (size_t)KSEL * DIM * 4);
  CARVE2(u64*, fbkey, 8);
  CARVE2(int*, hist1, 4096 * 4);
  CARVE2(int*, hist2, 4096 * 4);
  CARVE2(int*, ccnt, 16);
  CARVE2(int*, kcnt, 16);
  size_t zBsize = ho - zB;
  // not zeroed (kernel-initialized):
  CARVE2(int*, krank, (size_t)N_NODES * 4);           // compact_kernel writes all
  CARVE2(u64*, cand, (size_t)CANDCAP * 8);
  CARVE2(u64*, kkey, (size_t)(KSEL + 16) * 8);
  CARVE2(int*, kidx, (size_t)(KSEL + 16) * 4);
  CARVE2(int*, selb, 4 * 4);                          // b0, rem1, b1, rem2
  CARVE2(u64*, Tkey, 8);
  float* xp2 = sums;   // sums dead after gemm_tiled_div
  (void)ws_size; (void)out_size; (void)n_in; (void)in_sizes;

  const int eb  = (N_EDGES + 255) / 256;             // 3125
  const int nb  = (N_NODES + 255) / 256;             // 196
  const int kbs = (KSEL + 255) / 256;                // 20
  const int pcb = (N_NODES + PCH - 1) / PCH;         // 196
  const int mcb = (N_NODES + MCH - 1) / MCH;         // 3125
  const int gtb = (N_NODES + 31) / 32;               // 1563 tiled-GEMM blocks
  const int gkb = (KSEL + 31) / 32;                  // 157

  hipMemsetAsync(ws + zA, 0, zAsize, stream);

  // GCN1: h = x@W1 (tiled); CSR by col; fused gather
  gemm_tiled<<<gtb, 256, 0, stream>>>(x, W1, h, N_NODES);
  deg_kernel<<<eb, 256, 0, stream>>>(row, col, deg1, deg2);
  rsqrt_kernel<<<nb, 256, 0, stream>>>(deg1, dinv, N_NODES);
  scan_local<<<nb, 256, 0, stream>>>(deg1, start, bsum, N_NODES);
  scan_bsum<<<1, 256, 0, stream>>>(bsum, nb);
  scan_add<<<nb, 256, 0, stream>>>(start, bsum, N_NODES);
  fill_ecsr<<<eb, 256, 0, stream>>>(row, col, start, cursor, payload);
  gcn1_gather<<<N_NODES, DIM, 0, stream>>>(payload, start, deg1, dinv, h, b1, wscore,
                                           B, gate, key);
  // h region now free
  hipMemsetAsync(ws + zB, 0, zBsize, stream);

  // top-K: radix-select threshold (2x 4096-bin passes), then rank kept only
  hist1_kernel<<<nb, 256, 0, stream>>>(key, hist1);
  pick_kernel<<<1, 256, 0, stream>>>(hist1, KSEL, selb, /*rem_in*/0, /*bin_out*/0, /*rem_out*/1);
  hist2_kernel<<<nb, 256, 0, stream>>>(key, selb, hist2);
  pick_kernel<<<1, 256, 0, stream>>>(hist2, -1, selb, /*rem_in*/1, /*bin_out*/2, /*rem_out*/3);
  collect_kernel<<<nb, 256, 0, stream>>>(key, selb, cand, ccnt);
  thresh_kernel<<<1, 256, 0, stream>>>(cand, ccnt, selb, Tkey);
  compact_kernel<<<nb, 256, 0, stream>>>(key, Tkey, krank, kkey, kidx, kcnt);
  krank_kernel<<<kbs, 256, 0, stream>>>(kkey, kidx, deg2, krank, fbkey);

  // clustering
  bestneigh_kernel<<<eb, 256, 0, stream>>>(row, col, krank, deg2, best);
  assign_kernel<<<nb, 256, 0, stream>>>(krank, best, row, col, fbkey, cluster, counts);

  // mean pool (chunked segmented reduction) + coarse degrees (balanced)
  scan_small<<<1, 256, 0, stream>>>(counts, startn, KSEL);
  fill_members<<<nb, 256, 0, stream>>>(cluster, startn, cursorn, members);
  pool_chunk<<<pcb, DIM, 0, stream>>>(members, startn, B, gate, sums);
  cdeg_kernel<<<nb, 256, 0, stream>>>(payload, start, deg1, cluster, degc);
  rsqrt_kernel<<<kbs, 256, 0, stream>>>(degc, dinvc, KSEL);

  // GCN2 on coarse graph via fine edge-CSR (members-ordered, low-atomic)
  gemm_tiled_div<<<gkb, 256, 0, stream>>>(sums, counts, W2, h2, KSEL);
  coarse_chunk<<<mcb, DIM, 0, stream>>>(members, startn, cluster, start, deg1, payload,
                                        dinvc, h2, agg2);
  combine2<<<(KSEL * DIM) / 256, 256, 0, stream>>>(agg2, h2, dinvc, b2, xp2);

  // broadcast + skip (tiled GEMM + fused epilogue)
  final_tiled<<<gtb, 256, 0, stream>>>(B, Wsk, bsk, xp2, cluster, out);
}

// Round 12
// 868.269 us; speedup vs baseline: 1.0682x; 1.0682x over previous
//
#include <hip/hip_runtime.h>
#include <cstdint>

#define N_NODES 50000
#define N_EDGES 800000
#define DIM 128
#define KSEL 5000
#define MCONST (2 * N_EDGES + 2)   // 1600002
#define PCH 256     // pool chunk (members per block)
#define CANDCAP 8192
#define TM 4        // rows per thread in tiled GEMM (block covers 32 rows)

typedef unsigned long long u64;
typedef uint32_t u32;

// ---------- tiled GEMM core: Y[r][c] = sum_k X[r][k]*W[k][c], W is 128x128 ----
#define FMA4(a, s, w) { a.x = fmaf(s, w.x, a.x); a.y = fmaf(s, w.y, a.y); \
                        a.z = fmaf(s, w.z, a.z); a.w = fmaf(s, w.w, a.w); }

__device__ __forceinline__ void gemm_tile_body(const float4* __restrict__ W4,
                                               float xs[32][DIM], float4 acc[TM],
                                               int tx, int ty) {
#pragma unroll 8
  for (int k4 = 0; k4 < 32; k4++) {
    float4 xv[TM];
#pragma unroll
    for (int m = 0; m < TM; m++) xv[m] = *(const float4*)&xs[ty + 8 * m][k4 * 4];
#pragma unroll
    for (int j = 0; j < 4; j++) {
      float4 w = W4[(k4 * 4 + j) * 32 + tx];
#pragma unroll
      for (int m = 0; m < TM; m++) {
        float s = (j == 0) ? xv[m].x : (j == 1) ? xv[m].y : (j == 2) ? xv[m].z : xv[m].w;
        FMA4(acc[m], s, w);
      }
    }
  }
}

__global__ void gemm_tiled(const float* __restrict__ X, const float* __restrict__ W,
                           float* __restrict__ Y, int nrows) {
  __shared__ float xs[32][DIM];
  int tx = threadIdx.x & 31, ty = threadIdx.x >> 5;
  int rbase = blockIdx.x * 32;
  int nval = min(32, nrows - rbase);
  const float4* X4 = (const float4*)(X + (size_t)rbase * DIM);
  float4* xs4 = (float4*)&xs[0][0];
  for (int i = threadIdx.x; i < 32 * 32; i += 256)
    if ((i >> 5) < nval) xs4[i] = X4[i];
  __syncthreads();
  float4 acc[TM];
#pragma unroll
  for (int m = 0; m < TM; m++) acc[m] = make_float4(0.f, 0.f, 0.f, 0.f);
  gemm_tile_body((const float4*)W, xs, acc, tx, ty);
#pragma unroll
  for (int m = 0; m < TM; m++) {
    int r = rbase + ty + 8 * m;
    if (r < nrows) ((float4*)(Y + (size_t)r * DIM))[tx] = acc[m];
  }
}

// variant: rows pre-divided by counts (mean pool) during staging
__global__ void gemm_tiled_div(const float* __restrict__ S, const int* __restrict__ counts,
                               const float* __restrict__ W, float* __restrict__ Y, int nrows) {
  __shared__ float xs[32][DIM];
  int tx = threadIdx.x & 31, ty = threadIdx.x >> 5;
  int rbase = blockIdx.x * 32;
  int nval = min(32, nrows - rbase);
  const float4* X4 = (const float4*)(S + (size_t)rbase * DIM);
  float4* xs4 = (float4*)&xs[0][0];
  for (int i = threadIdx.x; i < 32 * 32; i += 256) {
    int rr = i >> 5;
    if (rr < nval) {
      float inv = 1.0f / (float)max(counts[rbase + rr], 1);
      float4 v = X4[i];
      v.x *= inv; v.y *= inv; v.z *= inv; v.w *= inv;
      xs4[i] = v;
    }
  }
  __syncthreads();
  float4 acc[TM];
#pragma unroll
  for (int m = 0; m < TM; m++) acc[m] = make_float4(0.f, 0.f, 0.f, 0.f);
  gemm_tile_body((const float4*)W, xs, acc, tx, ty);
#pragma unroll
  for (int m = 0; m < TM; m++) {
    int r = rbase + ty + 8 * m;
    if (r < nrows) ((float4*)(Y + (size_t)r * DIM))[tx] = acc[m];
  }
}

// variant: epilogue adds b_skip and xp2[cluster[r]] (the broadcast+skip fusion)
__global__ void final_tiled(const float* __restrict__ x1, const float* __restrict__ Wsk,
                            const float* __restrict__ bsk, const float* __restrict__ xp2,
                            const int* __restrict__ cluster, float* __restrict__ out) {
  __shared__ float xs[32][DIM];
  int tx = threadIdx.x & 31, ty = threadIdx.x >> 5;
  int rbase = blockIdx.x * 32;
  int nval = min(32, N_NODES - rbase);
  const float4* X4 = (const float4*)(x1 + (size_t)rbase * DIM);
  float4* xs4 = (float4*)&xs[0][0];
  for (int i = threadIdx.x; i < 32 * 32; i += 256)
    if ((i >> 5) < nval) xs4[i] = X4[i];
  __syncthreads();
  float4 acc[TM];
#pragma unroll
  for (int m = 0; m < TM; m++) acc[m] = make_float4(0.f, 0.f, 0.f, 0.f);
  gemm_tile_body((const float4*)Wsk, xs, acc, tx, ty);
  float4 bv = ((const float4*)bsk)[tx];
#pragma unroll
  for (int m = 0; m < TM; m++) {
    int r = rbase + ty + 8 * m;
    if (r < N_NODES) {
      int cl = cluster[r];
      cl = (cl < 0) ? 0 : (cl >= KSEL ? KSEL - 1 : cl);   // defensive clamp
      float4 pv = ((const float4*)(xp2 + (size_t)cl * DIM))[tx];
      float4 o;
      o.x = acc[m].x + bv.x + pv.x;
      o.y = acc[m].y + bv.y + pv.y;
      o.z = acc[m].z + bv.z + pv.z;
      o.w = acc[m].w + bv.w + pv.w;
      ((float4*)(out + (size_t)r * DIM))[tx] = o;
    }
  }
  if (blockIdx.x == 0 && threadIdx.x == 0) out[(size_t)N_NODES * DIM] = 0.0f;  // tuple scalar
}

// ---------------- degree counts ----------------
__global__ void deg_kernel(const int* __restrict__ row, const int* __restrict__ col,
                           int* deg1, int* deg2) {
  int e = blockIdx.x * blockDim.x + threadIdx.x;
  if (e < N_EDGES) {
    atomicAdd(&deg1[col[e]], 1);   // in-degree at col (GCN norm)
    atomicAdd(&deg2[row[e]], 1);   // bincount(row) (topk-pool degree)
  }
}

__global__ void rsqrt_kernel(const int* __restrict__ deg, float* __restrict__ dinv, int n) {
  int i = blockIdx.x * blockDim.x + threadIdx.x;
  if (i < n) dinv[i] = rsqrtf((float)deg[i] + 1.0f);
}

// ---------------- hierarchical exclusive scan (N_NODES) ----------------
__global__ void scan_local(const int* __restrict__ in, int* __restrict__ out,
                           int* __restrict__ bsum, int n) {
  __shared__ int s[256];
  int i = blockIdx.x * 256 + threadIdx.x;
  int v = (i < n) ? in[i] : 0;
  s[threadIdx.x] = v;
  __syncthreads();
  for (int off = 1; off < 256; off <<= 1) {
    int t = (threadIdx.x >= off) ? s[threadIdx.x - off] : 0;
    __syncthreads();
    s[threadIdx.x] += t;
    __syncthreads();
  }
  if (i < n) out[i] = s[threadIdx.x] - v;   // exclusive
  if (threadIdx.x == 255) bsum[blockIdx.x] = s[255];
}

__global__ void scan_bsum(int* bsum, int nb) {
  __shared__ int s[256];
  int v = (threadIdx.x < nb) ? bsum[threadIdx.x] : 0;
  s[threadIdx.x] = v;
  __syncthreads();
  for (int off = 1; off < 256; off <<= 1) {
    int t = (threadIdx.x >= off) ? s[threadIdx.x - off] : 0;
    __syncthreads();
    s[threadIdx.x] += t;
    __syncthreads();
  }
  if (threadIdx.x < nb) bsum[threadIdx.x] = s[threadIdx.x] - v;
}

__global__ void scan_add(int* out, const int* __restrict__ bsum, int n) {
  int i = blockIdx.x * 256 + threadIdx.x;
  if (i < n) out[i] += bsum[blockIdx.x];
}

// ---------------- single-block exclusive scan (n ~ 5000), writes out[n]=total -
__global__ void scan_small(const int* __restrict__ in, int* __restrict__ out, int n) {
  __shared__ int s[256];
  __shared__ int carry;
  if (threadIdx.x == 0) carry = 0;
  __syncthreads();
  for (int base = 0; base < n; base += 256) {
    int i = base + threadIdx.x;
    int v = (i < n) ? in[i] : 0;
    s[threadIdx.x] = v;
    __syncthreads();
    for (int off = 1; off < 256; off <<= 1) {
      int t = (threadIdx.x >= off) ? s[threadIdx.x - off] : 0;
      __syncthreads();
      s[threadIdx.x] += t;
      __syncthreads();
    }
    int c = carry;
    if (i < n) out[i] = c + s[threadIdx.x] - v;
    __syncthreads();
    if (threadIdx.x == 255) carry = c + s[255];
    __syncthreads();
  }
  if (threadIdx.x == 0) out[n] = carry;
}

// ---------------- CSR fills ----------------
__global__ void fill_ecsr(const int* __restrict__ row, const int* __restrict__ col,
                          const int* __restrict__ start, int* cursor, int* payload) {
  int e = blockIdx.x * blockDim.x + threadIdx.x;
  if (e < N_EDGES) {
    int c = col[e];
    int p = start[c] + atomicAdd(&cursor[c], 1);
    if (p >= 0 && p < N_EDGES) payload[p] = row[e];    // defensive bound
  }
}

__global__ void fill_members(const int* __restrict__ cluster, const int* __restrict__ startn,
                             int* cursorn, int* members) {
  int i = blockIdx.x * blockDim.x + threadIdx.x;
  if (i < N_NODES) {
    int c = cluster[i];
    int p = startn[c] + atomicAdd(&cursorn[c], 1);
    if (p >= 0 && p < N_NODES) members[p] = i;         // defensive bound
  }
}

// ---------------- GCN1 gather + combine + relu + score + key (fused) ---------
// inner loop unrolled x4: 4 independent (dinv, h-row) load pairs in flight.
__global__ void gcn1_gather(const int* __restrict__ srcs, const int* __restrict__ start,
                            const int* __restrict__ deg1, const float* __restrict__ dinv,
                            const float* __restrict__ h, const float* __restrict__ b1,
                            const float* __restrict__ wscore,
                            float* __restrict__ B, float* __restrict__ gate,
                            u64* __restrict__ key) {
  int i = blockIdx.x, t = threadIdx.x;
  int s0 = start[i], n = deg1[i];
  float di = dinv[i];
  float acc = 0.f;
  int k = 0;
  for (; k + 4 <= n; k += 4) {
    int r0 = srcs[s0 + k], r1 = srcs[s0 + k + 1], r2 = srcs[s0 + k + 2], r3 = srcs[s0 + k + 3];
    float w0 = dinv[r0], w1 = dinv[r1], w2 = dinv[r2], w3 = dinv[r3];
    float h0 = h[r0 * DIM + t], h1 = h[r1 * DIM + t];
    float h2v = h[r2 * DIM + t], h3 = h[r3 * DIM + t];
    acc = fmaf(w0, h0, acc);
    acc = fmaf(w1, h1, acc);
    acc = fmaf(w2, h2v, acc);
    acc = fmaf(w3, h3, acc);
  }
  for (; k < n; k++) {
    int r = srcs[s0 + k];
    acc = fmaf(dinv[r], h[r * DIM + t], acc);
  }
  float v = acc * di + di * di * h[i * DIM + t] + b1[t];
  v = v > 0.f ? v : 0.f;
  B[i * DIM + t] = v;
  __shared__ float red[DIM];
  red[t] = v * wscore[t];
  __syncthreads();
  for (int s = DIM / 2; s > 0; s >>= 1) {
    if (t < s) red[t] += red[t + s];
    __syncthreads();
  }
  if (t == 0) {
    float r = red[0];
    gate[i] = tanhf(r);
    u32 b = __float_as_uint(r);
    if ((b << 1) == 0u) b = 0u;                          // -0 -> +0
    u32 ord = (b & 0x80000000u) ? ~b : (b | 0x80000000u);
    key[i] = (((u64)(~ord)) << 32) | (u32)i;             // asc = desc value, tie asc idx
  }
}

// ============== top-K selection: radix-select threshold, then rank kept =======
__global__ void hist1_kernel(const u64* __restrict__ key, int* __restrict__ hist) {
  int i = blockIdx.x * blockDim.x + threadIdx.x;
  if (i < N_NODES) atomicAdd(&hist[(int)(key[i] >> 52)], 1);
}

__global__ void hist2_kernel(const u64* __restrict__ key, const int* __restrict__ selb,
                             int* __restrict__ hist) {
  int i = blockIdx.x * blockDim.x + threadIdx.x;
  if (i < N_NODES) {
    u64 k = key[i];
    if ((int)(k >> 52) == selb[0]) atomicAdd(&hist[(int)((k >> 40) & 0xFFF)], 1);
  }
}

__global__ void pick_kernel(const int* __restrict__ hist, int K_imm, int* __restrict__ selb,
                            int rem_in_slot, int bin_out_slot, int rem_out_slot) {
  __shared__ int s[256];
  int t = threadIdx.x;
  int base = t * 16;
  int loc[16];
  int sum = 0;
#pragma unroll
  for (int k = 0; k < 16; k++) { loc[k] = hist[base + k]; sum += loc[k]; }
  s[t] = sum;
  __syncthreads();
  for (int off = 1; off < 256; off <<= 1) {
    int v = (t >= off) ? s[t - off] : 0;
    __syncthreads();
    s[t] += v;
    __syncthreads();
  }
  int target = (K_imm >= 0) ? K_imm : selb[rem_in_slot];
  int prev = (t == 0) ? 0 : s[t - 1];
  if (prev < target && target <= s[t]) {      // exactly one thread
    int cum = prev;
#pragma unroll
    for (int k = 0; k < 16; k++) {
      cum += loc[k];
      if (cum >= target) {
        selb[bin_out_slot] = base + k;
        selb[rem_out_slot] = target - (cum - loc[k]);   // in [1, bincount]
        break;
      }
    }
  }
}

__global__ void collect_kernel(const u64* __restrict__ key, const int* __restrict__ selb,
                               u64* __restrict__ cand, int* __restrict__ ccnt) {
  int i = blockIdx.x * blockDim.x + threadIdx.x;
  if (i < N_NODES) {
    u64 k = key[i];
    if ((int)(k >> 52) == selb[0] && (int)((k >> 40) & 0xFFF) == selb[2]) {
      int p = atomicAdd(ccnt, 1);
      if (p < CANDCAP) cand[p] = k;
    }
  }
}

__global__ void thresh_kernel(const u64* __restrict__ cand, const int* __restrict__ ccnt,
                              const int* __restrict__ selb, u64* __restrict__ T) {
  int c = min(*ccnt, CANDCAP);
  int R = selb[3];
  for (int p = threadIdx.x; p < c; p += 256) {
    u64 kp = cand[p];
    int cnt = 0;
    for (int q = 0; q < c; q++) cnt += (cand[q] < kp) ? 1 : 0;
    if (cnt == R - 1) *T = kp;                           // unique keys: one writer
  }
}

__global__ void compact_kernel(const u64* __restrict__ key, const u64* __restrict__ T,
                               int* __restrict__ krank, u64* __restrict__ kkey,
                               int* __restrict__ kidx, int* __restrict__ kcnt) {
  int i = blockIdx.x * blockDim.x + threadIdx.x;
  if (i < N_NODES) {
    krank[i] = -1;
    u64 k = key[i];
    if (k <= *T) {
      int p = atomicAdd(kcnt, 1);
      if (p < KSEL + 16) {                               // capacity guard
        kkey[p] = k;
        kidx[p] = i;
      }
    }
  }
}

__global__ void krank_kernel(const u64* __restrict__ kkey, const int* __restrict__ kidx,
                             const int* __restrict__ deg2, int* __restrict__ krank,
                             u64* fbkey) {
  int p = blockIdx.x * blockDim.x + threadIdx.x;
  u64 mykey = (p < KSEL) ? kkey[p] : ~0ull;
  __shared__ u64 sk[256];
  int cnt = 0;
  for (int base = 0; base < KSEL; base += 256) {
    int j = base + threadIdx.x;
    sk[threadIdx.x] = (j < KSEL) ? kkey[j] : ~0ull;
    __syncthreads();
    int lim = min(256, KSEL - base);
#pragma unroll 4
    for (int q = 0; q < lim; q++) cnt += (sk[q] < mykey) ? 1 : 0;
    __syncthreads();
  }
  if (p < KSEL) {
    int node = kidx[p];
    if (node >= 0 && node < N_NODES) {                   // defensive bound
      krank[node] = cnt;
      u64 fk = (((u64)(deg2[node] + 1)) << 32) | (u32)(KSEL - 1 - cnt);
      atomicMax(fbkey, fk);
    }
  }
}

// ---------------- best kept neighbor per owner ----------------
__global__ void bestneigh_kernel(const int* __restrict__ row, const int* __restrict__ col,
                                 const int* __restrict__ krank, const int* __restrict__ deg2,
                                 u64* __restrict__ best) {
  int e = blockIdx.x * blockDim.x + threadIdx.x;
  if (e < N_EDGES) {
    int r = row[e], c = col[e];
    if (krank[c] >= 0) {  // (owner=r, neigh=c, order=2e)
      u64 comp = (u64)deg2[c] * (u64)MCONST + (u64)(MCONST - 1 - 2 * e);
      atomicMax(&best[r], comp + 1);
    }
    if (krank[r] >= 0) {  // (owner=c, neigh=r, order=2e+1)
      u64 comp = (u64)deg2[r] * (u64)MCONST + (u64)(MCONST - 2 - 2 * e);
      atomicMax(&best[c], comp + 1);
    }
  }
}

// ---------------- cluster assignment + counts ----------------
__global__ void assign_kernel(const int* __restrict__ krank, const u64* __restrict__ best,
                              const int* __restrict__ row, const int* __restrict__ col,
                              const u64* __restrict__ fbkey,
                              int* __restrict__ cluster, int* __restrict__ counts) {
  int i = blockIdx.x * blockDim.x + threadIdx.x;
  if (i >= N_NODES) return;
  int c;
  int rk = krank[i];
  if (rk >= 0) {
    c = rk;
  } else {
    u64 b = best[i];
    if (b > 0) {
      u64 comp = b - 1;
      int rem = (int)(comp % (u64)MCONST);
      int ord = MCONST - 1 - rem;
      int e = ord >> 1;
      int nb = (ord & 1) ? row[e] : col[e];
      c = krank[nb];
    } else {
      c = KSEL - 1 - (int)((*fbkey) & 0xffffffffu);
    }
  }
  c = (c < 0) ? 0 : (c >= KSEL ? KSEL - 1 : c);          // defensive clamp
  cluster[i] = c;
  atomicAdd(&counts[c], 1);
}

// ---------------- mean pool, merge-path chunked segmented reduction ----------
__global__ void pool_chunk(const int* __restrict__ members, const int* __restrict__ startn,
                           const float* __restrict__ x1, const float* __restrict__ gate,
                           float* __restrict__ sums) {
  int cb = blockIdx.x * PCH;
  if (cb >= N_NODES) return;
  int ce = min(cb + PCH, N_NODES);
  __shared__ int pl[PCH];
  for (int k = threadIdx.x; k < ce - cb; k += DIM) pl[k] = members[cb + k];
  __syncthreads();
  int lo = 0, hi = KSEL - 1;                 // largest c with startn[c] <= cb
  while (lo < hi) { int mid = (lo + hi + 1) >> 1; if (startn[mid] <= cb) lo = mid; else hi = mid - 1; }
  int c = lo;
  int segend = startn[c + 1];
  int t = threadIdx.x;
  float acc = 0.f;
  for (int k = cb; k < ce; k++) {
    int j = pl[k - cb];
    acc = fmaf(gate[j], x1[j * DIM + t], acc);
    int k1 = k + 1;
    if (k1 == segend || k1 == ce) {
      atomicAdd(&sums[c * DIM + t], acc);
      acc = 0.f;
      if (k1 == segend && k1 < ce) {
        while (c < KSEL - 1 && startn[c + 1] <= k1) c++;   // bounded advance
        segend = startn[c + 1];
      }
    }
  }
}

// ---------------- map cluster-of-source per CSR slot (edge-parallel) ----------
__global__ void map_csrc(const int* __restrict__ payload, const int* __restrict__ cluster,
                         int* __restrict__ csrc) {
  int p = blockIdx.x * blockDim.x + threadIdx.x;
  if (p < N_EDGES) csrc[p] = cluster[payload[p]];
}

// ---------------- coarse degrees via csrc (contiguous reads) ----------------
__global__ void cdeg_kernel(const int* __restrict__ csrc, const int* __restrict__ start,
                            const int* __restrict__ deg1, const int* __restrict__ cluster,
                            int* __restrict__ degc) {
  int v = blockIdx.x * blockDim.x + threadIdx.x;
  if (v >= N_NODES) return;
  int cv = cluster[v];
  int s0 = start[v], n = deg1[v], cnt = 0;
  for (int k = 0; k < n; k++) cnt += (csrc[s0 + k] != cv) ? 1 : 0;
  if (cnt) atomicAdd(&degc[cv], cnt);
}

// ---- coarse SpMM: node-per-block, branch-free, unrolled x4 for MLP ----------
// acc = sum over ALL in-edges of dinvc[cu]*h2[cu] ; subtract intra contribution
// (intra terms are each exactly dinvc[cv]*h2[cv]) -> no divergent branch,
// 4 independent h2-row loads in flight per unroll group.
__global__ void coarse_gather2(const int* __restrict__ csrc, const int* __restrict__ start,
                               const int* __restrict__ deg1, const int* __restrict__ cluster,
                               const float* __restrict__ dinvc, const float* __restrict__ h2,
                               float* __restrict__ agg2) {
  int v = blockIdx.x, t = threadIdx.x;
  int n = deg1[v];
  if (n == 0) return;
  int cv = cluster[v];
  int s0 = start[v];
  float acc = 0.f;
  int intra = 0;
  int k = 0;
  for (; k + 4 <= n; k += 4) {
    int c0 = csrc[s0 + k], c1 = csrc[s0 + k + 1], c2 = csrc[s0 + k + 2], c3 = csrc[s0 + k + 3];
    intra += (c0 == cv) + (c1 == cv) + (c2 == cv) + (c3 == cv);
    float w0 = dinvc[c0], w1 = dinvc[c1], w2 = dinvc[c2], w3 = dinvc[c3];
    float g0 = h2[c0 * DIM + t], g1 = h2[c1 * DIM + t];
    float g2 = h2[c2 * DIM + t], g3 = h2[c3 * DIM + t];
    acc = fmaf(w0, g0, acc);
    acc = fmaf(w1, g1, acc);
    acc = fmaf(w2, g2, acc);
    acc = fmaf(w3, g3, acc);
  }
  for (; k < n; k++) {
    int c0 = csrc[s0 + k];
    intra += (c0 == cv);
    acc = fmaf(dinvc[c0], h2[c0 * DIM + t], acc);
  }
  if (intra < n) {                           // at least one inter-cluster edge
    acc = fmaf(-(float)intra * dinvc[cv], h2[cv * DIM + t], acc);
    atomicAdd(&agg2[cv * DIM + t], acc);
  }
}

// ---------------- combine2: xp2 = agg2*dc + dc*dc*h2 + b2 ----------------
__global__ void combine2(const float* __restrict__ agg2, const float* __restrict__ h2,
                         const float* __restrict__ dinvc, const float* __restrict__ b2,
                         float* __restrict__ xp2) {
  int gid = blockIdx.x * blockDim.x + threadIdx.x;
  int c = gid >> 7, d = gid & 127;
  if (c < KSEL) {
    float dc = dinvc[c];
    xp2[gid] = agg2[gid] * dc + dc * dc * h2[gid] + b2[d];
  }
}

extern "C" void kernel_launch(void* const* d_in, const int* in_sizes, int n_in,
                              void* d_out, int out_size, void* d_ws, size_t ws_size,
                              hipStream_t stream) {
  const float* x      = (const float*)d_in[0];
  const int*   eidx   = (const int*)d_in[1];
  const float* W1     = (const float*)d_in[2];
  const float* b1     = (const float*)d_in[3];
  const float* W2     = (const float*)d_in[4];
  const float* b2     = (const float*)d_in[5];
  const float* wscore = (const float*)d_in[6];
  const float* Wsk    = (const float*)d_in[7];
  const float* bsk    = (const float*)d_in[8];
  float* out = (float*)d_out;

  const int* row = eidx;
  const int* col = eidx + N_EDGES;

  // ---- workspace carve (EVERY offset rounded to 16 B — misaligned u64
  // atomics fault on gfx950) ----
  char* ws = (char*)d_ws;
#define ALIGN16(v) (((v) + 15) & ~(size_t)15)
  size_t off = 0;
#define CARVE(ptr_t, name, bytes) ptr_t name = (ptr_t)(ws + off); off = ALIGN16(off + (bytes))
  size_t h_off = off;
  CARVE(float*, h, (size_t)N_NODES * DIM * 4);        // 25.6 MB (aliased below)
  CARVE(float*, B, (size_t)N_NODES * DIM * 4);        // x1
  CARVE(int*, payload, (size_t)N_EDGES * 4);          // edge CSR (by col)
  CARVE(u64*, key, (size_t)N_NODES * 8);
  CARVE(float*, gate, (size_t)N_NODES * 4);
  CARVE(float*, dinv, (size_t)N_NODES * 4);
  CARVE(int*, start, (size_t)N_NODES * 4);
  CARVE(int*, bsum, 256 * 4);
  // zone A: zero before deg/fill
  size_t zA = off;
  CARVE(int*, deg1, (size_t)N_NODES * 4);
  CARVE(int*, deg2, (size_t)N_NODES * 4);
  CARVE(int*, cursor, (size_t)N_NODES * 4);
  size_t zAsize = off - zA;

  // aliased into h's region (h is dead after gcn1_gather)
  size_t ho = h_off;
#define CARVE2(ptr_t, name, bytes) ptr_t name = (ptr_t)(ws + ho); ho = ALIGN16(ho + (bytes))
  CARVE2(int*, cluster, (size_t)N_NODES * 4);
  CARVE2(int*, members, (size_t)N_NODES * 4);
  CARVE2(int*, startn, (size_t)(KSEL + 1) * 4);
  CARVE2(float*, dinvc, (size_t)KSEL * 4);
  CARVE2(float*, h2, (size_t)KSEL * DIM * 4);
  CARVE2(int*, csrc, (size_t)N_EDGES * 4);            // cluster-of-source per CSR slot
  // zone B: zeroed after gcn1_gather
  size_t zB = ho;
  CARVE2(u64*, best, (size_t)N_NODES * 8);
  CARVE2(int*, counts, (size_t)KSEL * 4);
  CARVE2(int*, degc, (size_t)KSEL * 4);
  CARVE2(int*, cursorn, (size_t)KSEL * 4);
  CARVE2(float*, sums, (size_t)KSEL * DIM * 4);       // pool sums, then xp2
  CARVE2(float*, agg2, (size_t)KSEL * DIM * 4);
  CARVE2(u64*, fbkey, 8);
  CARVE2(int*, hist1, 4096 * 4);
  CARVE2(int*, hist2, 4096 * 4);
  CARVE2(int*, ccnt, 16);
  CARVE2(int*, kcnt, 16);
  size_t zBsize = ho - zB;
  // not zeroed (kernel-initialized):
  CARVE2(int*, krank, (size_t)N_NODES * 4);           // compact_kernel writes all
  CARVE2(u64*, cand, (size_t)CANDCAP * 8);
  CARVE2(u64*, kkey, (size_t)(KSEL + 16) * 8);
  CARVE2(int*, kidx, (size_t)(KSEL + 16) * 4);
  CARVE2(int*, selb, 4 * 4);                          // b0, rem1, b1, rem2
  CARVE2(u64*, Tkey, 8);
  float* xp2 = sums;   // sums dead after gemm_tiled_div
  (void)ws_size; (void)out_size; (void)n_in; (void)in_sizes;

  const int eb  = (N_EDGES + 255) / 256;             // 3125
  const int nb  = (N_NODES + 255) / 256;             // 196
  const int kbs = (KSEL + 255) / 256;                // 20
  const int pcb = (N_NODES + PCH - 1) / PCH;         // 196
  const int gtb = (N_NODES + 31) / 32;               // 1563 tiled-GEMM blocks
  const int gkb = (KSEL + 31) / 32;                  // 157

  hipMemsetAsync(ws + zA, 0, zAsize, stream);

  // GCN1: h = x@W1 (tiled); CSR by col; fused gather
  gemm_tiled<<<gtb, 256, 0, stream>>>(x, W1, h, N_NODES);
  deg_kernel<<<eb, 256, 0, stream>>>(row, col, deg1, deg2);
  rsqrt_kernel<<<nb, 256, 0, stream>>>(deg1, dinv, N_NODES);
  scan_local<<<nb, 256, 0, stream>>>(deg1, start, bsum, N_NODES);
  scan_bsum<<<1, 256, 0, stream>>>(bsum, nb);
  scan_add<<<nb, 256, 0, stream>>>(start, bsum, N_NODES);
  fill_ecsr<<<eb, 256, 0, stream>>>(row, col, start, cursor, payload);
  gcn1_gather<<<N_NODES, DIM, 0, stream>>>(payload, start, deg1, dinv, h, b1, wscore,
                                           B, gate, key);
  // h region now free
  hipMemsetAsync(ws + zB, 0, zBsize, stream);

  // top-K: radix-select threshold (2x 4096-bin passes), then rank kept only
  hist1_kernel<<<nb, 256, 0, stream>>>(key, hist1);
  pick_kernel<<<1, 256, 0, stream>>>(hist1, KSEL, selb, /*rem_in*/0, /*bin_out*/0, /*rem_out*/1);
  hist2_kernel<<<nb, 256, 0, stream>>>(key, selb, hist2);
  pick_kernel<<<1, 256, 0, stream>>>(hist2, -1, selb, /*rem_in*/1, /*bin_out*/2, /*rem_out*/3);
  collect_kernel<<<nb, 256, 0, stream>>>(key, selb, cand, ccnt);
  thresh_kernel<<<1, 256, 0, stream>>>(cand, ccnt, selb, Tkey);
  compact_kernel<<<nb, 256, 0, stream>>>(key, Tkey, krank, kkey, kidx, kcnt);
  krank_kernel<<<kbs, 256, 0, stream>>>(kkey, kidx, deg2, krank, fbkey);

  // clustering
  bestneigh_kernel<<<eb, 256, 0, stream>>>(row, col, krank, deg2, best);
  assign_kernel<<<nb, 256, 0, stream>>>(krank, best, row, col, fbkey, cluster, counts);

  // mean pool (chunked segmented reduction) + csrc map + coarse degrees
  scan_small<<<1, 256, 0, stream>>>(counts, startn, KSEL);
  fill_members<<<nb, 256, 0, stream>>>(cluster, startn, cursorn, members);
  pool_chunk<<<pcb, DIM, 0, stream>>>(members, startn, B, gate, sums);
  map_csrc<<<eb, 256, 0, stream>>>(payload, cluster, csrc);
  cdeg_kernel<<<nb, 256, 0, stream>>>(csrc, start, deg1, cluster, degc);
  rsqrt_kernel<<<kbs, 256, 0, stream>>>(degc, dinvc, KSEL);

  // GCN2 on coarse graph via fine edge-CSR (csrc, node-per-block, MLP x4)
  gemm_tiled_div<<<gkb, 256, 0, stream>>>(sums, counts, W2, h2, KSEL);
  coarse_gather2<<<N_NODES, DIM, 0, stream>>>(csrc, start, deg1, cluster, dinvc, h2, agg2);
  combine2<<<(KSEL * DIM) / 256, 256, 0, stream>>>(agg2, h2, dinvc, b2, xp2);

  // broadcast + skip (tiled GEMM + fused epilogue)
  final_tiled<<<gtb, 256, 0, stream>>>(B, Wsk, bsk, xp2, cluster, out);
}